// Round 1
// 231.952 us; speedup vs baseline: 1.0183x; 1.0183x over previous
//
#include <hip/hip_runtime.h>

#define S_LEN 2048
#define DMODEL 768
#define NH 12
#define DHEAD 64
#define BATCH 4
#define MROWS (BATCH * S_LEN)  // 8192
#define NQKV 2304              // 3*DMODEL
#define LOG2E 1.4426950408889634f

using short8 = __attribute__((ext_vector_type(8))) short;
using f32x4  = __attribute__((ext_vector_type(4))) float;
using f32x16 = __attribute__((ext_vector_type(16))) float;

typedef const __attribute__((address_space(1))) void* gas_ptr;
typedef __attribute__((address_space(3))) void* las_ptr;

__device__ __forceinline__ void gl2lds16(const void* g, void* l) {
  __builtin_amdgcn_global_load_lds((gas_ptr)(unsigned long long)g,
                                   (las_ptr)(unsigned int)(unsigned long long)l,
                                   16, 0, 0);
}

// 2^x via raw v_exp_f32
__device__ __forceinline__ float fexp2(float x) {
  float r;
  asm("v_exp_f32 %0, %1" : "=v"(r) : "v"(x));
  return r;
}

// packed f32x2 -> bf16x2 (RNE), lo in [15:0]
__device__ __forceinline__ unsigned cvtpk(float lo, float hi) {
  unsigned r;
  asm("v_cvt_pk_bf16_f32 %0, %1, %2" : "=v"(r) : "v"(lo), "v"(hi));
  return r;
}

// swap a.hi32lanes <-> b.lo32lanes ; after: a=[a.lo,b.lo], b=[a.hi,b.hi]
__device__ __forceinline__ void plswap(unsigned &a, unsigned &b) {
  asm("v_permlane32_swap_b32 %0, %1" : "+v"(a), "+v"(b));
}

// Fused prep: fp32->bf16 for X and the 3 W's, mask -> (mask-10)*log2e
__global__ __launch_bounds__(256) void prep_kernel(
    const float* __restrict__ hs, const float* __restrict__ Wq,
    const float* __restrict__ Wk, const float* __restrict__ Wv,
    const float* __restrict__ mask,
    unsigned short* __restrict__ Xb, unsigned short* __restrict__ Wall,
    float* __restrict__ mask2)
{
  const int NX = MROWS * DMODEL / 4;
  const int NW = DMODEL * DMODEL / 4;
  const int NM = (BATCH * S_LEN) / 4;
  int i = blockIdx.x * 256 + threadIdx.x;
  if (i < NX) {
    float4 f = ((const float4*)hs)[i];
    uint2 o = { cvtpk(f.x, f.y), cvtpk(f.z, f.w) };
    ((uint2*)Xb)[i] = o;
  } else if (i < NX + 3 * NW) {
    int j = i - NX;
    int sec = j / NW, r = j - sec * NW;
    const float* src = (sec == 0) ? Wq : (sec == 1) ? Wk : Wv;
    float4 f = ((const float4*)src)[r];
    uint2 o = { cvtpk(f.x, f.y), cvtpk(f.z, f.w) };
    ((uint2*)(Wall + (size_t)sec * DMODEL * DMODEL))[r] = o;
  } else if (i < NX + 3 * NW + NM) {
    int r = i - NX - 3 * NW;
    float4 m = ((const float4*)mask)[r];
    float4 o = { (m.x - 10.f) * LOG2E, (m.y - 10.f) * LOG2E,
                 (m.z - 10.f) * LOG2E, (m.w - 10.f) * LOG2E };
    ((float4*)mask2)[r] = o;
  }
}

// Out[m,n] = sum_k X[m,k]*Wall[n,k] + bias(n); Q section pre-scaled 1/8*log2e.
__global__ __launch_bounds__(256) void qkv_gemm(
    const unsigned short* __restrict__ Xb,   // [8192][768]
    const unsigned short* __restrict__ Wall, // [2304][768]
    const float* __restrict__ bq,
    const float* __restrict__ bk,
    const float* __restrict__ bv,
    unsigned short* __restrict__ Out)        // [8192][2304]
{
  __shared__ __align__(16) short As[128][64];
  __shared__ __align__(16) short Bs[128][64];

  int m0 = blockIdx.y * 128;
  int n0 = blockIdx.x * 128;
  int t = threadIdx.x;
  int w = t >> 6, lane = t & 63, lg = lane >> 4, lc = lane & 15;
  int wr = (w >> 1) * 64, wc = (w & 1) * 64;

  int srow = lane >> 3;
  int schunk = (lane & 7) ^ srow;

  f32x4 acc[4][4] = {};

  for (int k0 = 0; k0 < DMODEL; k0 += 64) {
    __syncthreads();
    for (int it = 0; it < 4; ++it) {
      int rb = w * 32 + it * 8;
      int r = rb + srow;
      gl2lds16(&Xb[(size_t)(m0 + r) * DMODEL + k0 + schunk * 8], &As[rb][0]);
      gl2lds16(&Wall[(size_t)(n0 + r) * DMODEL + k0 + schunk * 8], &Bs[rb][0]);
    }
    __syncthreads();
    for (int ks = 0; ks < 2; ++ks) {
      short8 a[4], b[4];
      for (int mt = 0; mt < 4; ++mt)
        a[mt] = *(const short8*)&As[wr + mt * 16 + lc][(((ks * 4 + lg) ^ (lc & 7))) * 8];
      for (int nt = 0; nt < 4; ++nt)
        b[nt] = *(const short8*)&Bs[wc + nt * 16 + lc][(((ks * 4 + lg) ^ (lc & 7))) * 8];
      for (int mt = 0; mt < 4; ++mt)
        for (int nt = 0; nt < 4; ++nt)
          acc[mt][nt] = __builtin_amdgcn_mfma_f32_16x16x32_bf16(a[mt], b[nt], acc[mt][nt], 0, 0, 0);
    }
  }

  for (int nt = 0; nt < 4; ++nt) {
    int col = n0 + wc + nt * 16 + lc;
    float bb = (col < 768) ? bq[col] : (col < 1536) ? bk[col - 768] : bv[col - 1536];
    float sc = (col < 768) ? (0.125f * LOG2E) : 1.0f;
    for (int mt = 0; mt < 4; ++mt) {
      int row = m0 + wr + mt * 16 + lg * 4;
      for (int i = 0; i < 4; ++i) {
        float v = (acc[mt][nt][i] + bb) * sc;
        Out[(size_t)(row + i) * NQKV + col] = (unsigned short)cvtpk(v, v);
      }
    }
  }
}

// V section of QKV -> Vt [b][h][d][s]
__global__ __launch_bounds__(256) void v_transpose(
    const unsigned short* __restrict__ QKV,
    unsigned short* __restrict__ Vt)
{
  int st = blockIdx.x, h = blockIdx.y, b = blockIdx.z;
  __shared__ __align__(16) short Ls[64][72];
  int t = threadIdx.x;
  int s0 = st * 64;
  int lr = t >> 3, ls = (t & 7) * 8;
  for (int it = 0; it < 2; ++it) {
    int r = lr + it * 32;
    *(int4*)&Ls[r][ls] =
        *(const int4*)&QKV[(size_t)(b * S_LEN + s0 + r) * NQKV + 1536 + h * DHEAD + ls];
  }
  __syncthreads();
  int d = t & 63, sq = t >> 6;
  size_t obase = ((size_t)((b * NH + h) * DHEAD + d)) * S_LEN + s0;
  for (int it = 0; it < 2; ++it) {
    int ss = sq + it * 4;
    short8 vv;
    for (int j = 0; j < 8; ++j) vv[j] = Ls[ss * 8 + j][d];
    *(short8*)&Vt[obase + ss * 8] = vv;
  }
}

// Flash attention, 32x32x16 MFMA, fixed-max softmax (base-2 domain).
// Block = (128 q, h, b); 4 waves x 32 q each; 64-key tiles, double-buffered LDS,
// P kept fully in registers (cvt_pk + permlane32_swap), no P LDS round-trip.
__global__ __launch_bounds__(256, 4) void flash_attn(
    const unsigned short* __restrict__ QKV,  // [8192][2304]; Q pre-scaled log2e/8
    const unsigned short* __restrict__ Vt,   // [48*64][2048]
    const float* __restrict__ mask2,         // (mask-10)*log2e, [B][S]
    float* __restrict__ out)                 // [B][S][768]
{
  int qt = blockIdx.x, h = blockIdx.y, b = blockIdx.z;
  __shared__ __align__(16) short Ks[2][64][64];    // swizzled [key][d]
  __shared__ __align__(16) short Vts[2][64][64];   // swizzled [d][key]

  int t = threadIdx.x, w = t >> 6, lane = t & 63;
  int m31 = lane & 31, hf = lane >> 5;  // 32-row index, half
  int q0 = qt * 128;
  int srow = lane >> 3;
  int schunk = (lane & 7) ^ srow;

  // Q B-frags: loop-invariant, direct from global. B[k=d][n=q]: n=m31, k=8*hf+j
  short8 qf[4];
  {
    size_t qrow = (size_t)(b * S_LEN + q0 + w * 32 + m31) * NQKV + h * DHEAD;
#pragma unroll
    for (int kk = 0; kk < 4; ++kk)
      qf[kk] = *(const short8*)&QKV[qrow + kk * 16 + hf * 8];
  }

  float lsum = 0.f;                    // l for q = m31 (this lane's column)
  f32x16 o[2] = {};                    // O tiles: d in {nt*32 + m31}
  size_t vtbase = (size_t)((b * NH + h) * DHEAD) * S_LEN;
  size_t kbase0 = (size_t)(b * S_LEN) * NQKV + 768 + h * DHEAD;
  const float* mrow = mask2 + (size_t)b * S_LEN;

  // prologue: stage tile 0 into buffer 0
#pragma unroll
  for (int it = 0; it < 2; ++it) {
    int rb = w * 16 + it * 8;
    int r = rb + srow;
    gl2lds16(&QKV[kbase0 + (size_t)r * NQKV + schunk * 8], &Ks[0][rb][0]);
    gl2lds16(&Vt[vtbase + (size_t)r * S_LEN + schunk * 8], &Vts[0][rb][0]);
  }

  int buf = 0;
  for (int kt = 0; kt < S_LEN / 64; ++kt) {
    int k0 = kt * 64;
    __syncthreads();  // tile kt resident (vmcnt drained); prev compute done

    // prefetch next tile into buf^1 (clamped redundant reload on last iter)
    {
      int ktn = (kt + 1 < S_LEN / 64) ? (kt + 1) : kt;
      int k0n = ktn * 64;
#pragma unroll
      for (int it = 0; it < 2; ++it) {
        int rb = w * 16 + it * 8;
        int r = rb + srow;
        gl2lds16(&QKV[kbase0 + (size_t)(k0n + r) * NQKV + schunk * 8], &Ks[buf ^ 1][rb][0]);
        gl2lds16(&Vt[vtbase + (size_t)r * S_LEN + k0n + schunk * 8], &Vts[buf ^ 1][rb][0]);
      }
    }

    // S^T[key][q] = K·Q^T: A=K rows (2 mt tiles of 32 keys), B=qf. k-dim=64 (4 kk)
    f32x16 s[2] = {};
    __builtin_amdgcn_s_setprio(1);
#pragma unroll
    for (int kk = 0; kk < 4; ++kk)
#pragma unroll
      for (int mt = 0; mt < 2; ++mt) {
        int r = mt * 32 + m31;
        short8 ak = *(const short8*)&Ks[buf][r][((kk * 2 + hf) ^ (r & 7)) * 8];
        s[mt] = __builtin_amdgcn_mfma_f32_32x32x16_bf16(ak, qf[kk], s[mt], 0, 0, 0);
      }
    __builtin_amdgcn_s_setprio(0);

    // p = 2^(s + mask2) (everything pre-scaled by log2e)
    // key = 32mt + 8g + 4hf + i ; q = m31. Pack to bf16 pairs in-register.
    unsigned pw[2][4][2];
#pragma unroll
    for (int mt = 0; mt < 2; ++mt)
#pragma unroll
      for (int g = 0; g < 4; ++g) {
        float4 mv = *(const float4*)&mrow[k0 + mt * 32 + g * 8 + hf * 4];
        float p0 = fexp2(s[mt][g * 4 + 0] + mv.x);
        float p1 = fexp2(s[mt][g * 4 + 1] + mv.y);
        float p2 = fexp2(s[mt][g * 4 + 2] + mv.z);
        float p3 = fexp2(s[mt][g * 4 + 3] + mv.w);
        lsum += (p0 + p1) + (p2 + p3);
        pw[mt][g][0] = cvtpk(p0, p1);  // keys 32mt+8g+4hf+{0,1}
        pw[mt][g][1] = cvtpk(p2, p3);  // keys 32mt+8g+4hf+{2,3}
      }

    // Build PV A-frags via permlane32_swap; O[q][d] += P·V
    // frag(kk) lane(hf) needs keys 16kk+8hf+{0..7}; swap merges lane-halves.
#pragma unroll
    for (int mt = 0; mt < 2; ++mt)
#pragma unroll
      for (int kk2 = 0; kk2 < 2; ++kk2) {
        unsigned a0 = pw[mt][2 * kk2][0], b0 = pw[mt][2 * kk2 + 1][0];
        unsigned a1 = pw[mt][2 * kk2][1], b1 = pw[mt][2 * kk2 + 1][1];
        plswap(a0, b0);  // a0=[keys+0,1 | +8,9]   b0=[keys+4,5 | +12,13]
        plswap(a1, b1);  // a1=[keys+2,3 | +10,11] b1=[keys+6,7 | +14,15]
        union { unsigned u[4]; short8 v; } fr;
        fr.u[0] = a0; fr.u[1] = a1; fr.u[2] = b0; fr.u[3] = b1;
        int kk = mt * 2 + kk2;
        __builtin_amdgcn_s_setprio(1);
#pragma unroll
        for (int nt = 0; nt < 2; ++nt) {
          int r = nt * 32 + m31;
          short8 bvv = *(const short8*)&Vts[buf][r][((kk * 2 + hf) ^ (r & 7)) * 8];
          o[nt] = __builtin_amdgcn_mfma_f32_32x32x16_bf16(fr.v, bvv, o[nt], 0, 0, 0);
        }
        __builtin_amdgcn_s_setprio(0);
      }

    buf ^= 1;
  }

  // final l for q=m31: own half + partner half, once
  lsum += __shfl_xor(lsum, 32, 64);
  float inv = 1.0f / lsum;
  // broadcast inv to C-layout rows: row q = (r&3) + 8*(r>>2) + 4*hf
  float lv[16];
#pragma unroll
  for (int r = 0; r < 16; ++r)
    lv[r] = __shfl(inv, (r & 3) + 8 * (r >> 2) + 4 * hf, 64);

  for (int nt = 0; nt < 2; ++nt)
    for (int r = 0; r < 16; ++r) {
      int qrow = (r & 3) + 8 * (r >> 2) + 4 * hf;
      int q = q0 + w * 32 + qrow;
      out[(size_t)(b * S_LEN + q) * DMODEL + h * DHEAD + nt * 32 + m31] = o[nt][r] * lv[r];
    }
}

extern "C" void kernel_launch(void* const* d_in, const int* in_sizes, int n_in,
                              void* d_out, int out_size, void* d_ws, size_t ws_size,
                              hipStream_t stream) {
  const float* hs   = (const float*)d_in[0];
  const float* mask = (const float*)d_in[1];
  const float* Wq   = (const float*)d_in[2];
  const float* bq   = (const float*)d_in[3];
  const float* Wk   = (const float*)d_in[4];
  const float* bk   = (const float*)d_in[5];
  const float* Wv   = (const float*)d_in[6];
  const float* bv   = (const float*)d_in[7];
  float* out = (float*)d_out;

  char* ws = (char*)d_ws;
  const size_t XB_BYTES   = (size_t)MROWS * DMODEL * 2;
  const size_t QKV_BYTES  = (size_t)MROWS * NQKV * 2;
  const size_t WALL_BYTES = (size_t)NQKV * DMODEL * 2;
  unsigned short* Xb    = (unsigned short*)ws;
  unsigned short* QKV   = (unsigned short*)(ws + XB_BYTES);
  unsigned short* Wall  = (unsigned short*)(ws + XB_BYTES + QKV_BYTES);
  float*          mask2 = (float*)(ws + XB_BYTES + QKV_BYTES + WALL_BYTES);
  unsigned short* Vtg   = Xb;  // Xb dead after qkv_gemm

  const int NX = MROWS * DMODEL / 4;
  const int NW = DMODEL * DMODEL / 4;
  const int NM = (BATCH * S_LEN) / 4;
  int nprep = NX + 3 * NW + NM;
  prep_kernel<<<(nprep + 255) / 256, 256, 0, stream>>>(hs, Wq, Wk, Wv, mask, Xb, Wall, mask2);

  qkv_gemm<<<dim3(NQKV / 128, MROWS / 128), 256, 0, stream>>>(Xb, Wall, bq, bk, bv, QKV);

  v_transpose<<<dim3(S_LEN / 64, NH, BATCH), 256, 0, stream>>>(QKV, Vtg);

  flash_attn<<<dim3(S_LEN / 128, NH, BATCH), 256, 0, stream>>>(QKV, Vtg, mask2, out);
}